// Round 1
// baseline (601.211 us; speedup 1.0000x reference)
//
#include <hip/hip_runtime.h>
#include <math.h>

// Problem constants (B, C, H, W) = (8, 512, 32, 32), NUM_HEADS = 8
namespace {
constexpr int kB = 8;
constexpr int kC = 512;
constexpr int kN = 1024;   // H*W
constexpr int k3C = 1536;
constexpr int kNH = 8;
constexpr int kHD = 64;
constexpr float kScale = 0.125f;  // hd^-0.5 = 1/8
}

// ---------------------------------------------------------------------------
// Generic per-batch GEMM: out[b][o][n] = bias[o] + sum_c w[o][c] * xin[b][c][n]
// K = 512, N = 1024 fixed; M passed (1536 for qkv, 512 for proj).
// 128x128 tile, BK=16, 8x8 micro-tile split as 2x2 blocks of 4x4 so each
// ds_read_b128 wave access spans 64 consecutive words (2 lanes/bank = free).
// ---------------------------------------------------------------------------
__global__ __launch_bounds__(256) void gemm_wx(const float* __restrict__ w,
                                               const float* __restrict__ xin,
                                               float* __restrict__ out,
                                               const float* __restrict__ bias,
                                               int M) {
    const int b = blockIdx.z;
    const int o0 = blockIdx.y * 128;
    const int n0 = blockIdx.x * 128;
    const int tid = threadIdx.x;
    const int tx = tid & 15;   // n direction
    const int ty = tid >> 4;   // o direction

    __shared__ __align__(16) float As[16][132];  // [c][o], +4 pad keeps 16B align
    __shared__ __align__(16) float Bs[16][132];  // [c][n]

    const float* xb = xin + (size_t)b * kC * kN;
    float acc[2][2][4][4] = {};

    for (int k0 = 0; k0 < kC; k0 += 16) {
        // Load A tile: w[o0+o][k0+c], 128x16, transposed into As[c][o]
        {
            const int c = tid & 15;
            const int obase = tid >> 4;  // 0..15
#pragma unroll
            for (int i = 0; i < 8; i++) {
                const int o = obase + i * 16;
                As[c][o] = w[(size_t)(o0 + o) * kC + (k0 + c)];
            }
        }
        // Load B tile: xin[b][k0+c][n0+n], 16x128
        {
            const int n = tid & 127;
            const int cbase = tid >> 7;  // 0..1
#pragma unroll
            for (int i = 0; i < 8; i++) {
                const int c = cbase + i * 2;
                Bs[c][n] = xb[(size_t)(k0 + c) * kN + (n0 + n)];
            }
        }
        __syncthreads();
#pragma unroll
        for (int kk = 0; kk < 16; kk++) {
            float a[2][4], bb[2][4];
            *(float4*)&a[0][0] = *(const float4*)&As[kk][ty * 4];
            *(float4*)&a[1][0] = *(const float4*)&As[kk][ty * 4 + 64];
            *(float4*)&bb[0][0] = *(const float4*)&Bs[kk][tx * 4];
            *(float4*)&bb[1][0] = *(const float4*)&Bs[kk][tx * 4 + 64];
#pragma unroll
            for (int ao = 0; ao < 2; ao++)
#pragma unroll
                for (int bo = 0; bo < 2; bo++)
#pragma unroll
                    for (int i = 0; i < 4; i++)
#pragma unroll
                        for (int j = 0; j < 4; j++)
                            acc[ao][bo][i][j] =
                                fmaf(a[ao][i], bb[bo][j], acc[ao][bo][i][j]);
        }
        __syncthreads();
    }

    float* ob = out + (size_t)b * M * kN;
#pragma unroll
    for (int ao = 0; ao < 2; ao++)
#pragma unroll
        for (int i = 0; i < 4; i++) {
            const int o = o0 + ao * 64 + ty * 4 + i;
            const float bv = bias ? bias[o] : 0.f;
#pragma unroll
            for (int bo = 0; bo < 2; bo++) {
                float4 st;
                st.x = acc[ao][bo][i][0] + bv;
                st.y = acc[ao][bo][i][1] + bv;
                st.z = acc[ao][bo][i][2] + bv;
                st.w = acc[ao][bo][i][3] + bv;
                *(float4*)&ob[(size_t)o * kN + n0 + bo * 64 + tx * 4] = st;
            }
        }
}

// ---------------------------------------------------------------------------
// Fused flash-style attention. qkv layout: [b][h*192 + {q:0-63,k:64-127,v:128-191}][n].
// Per block: one (b,h), 64-query tile. Online softmax over 16 key tiles of 64.
// S[nk][m] = scale * sum_d K[d][nk]*Q[d][m]; softmax over nk (keys);
// O[d][m] += V[d][nk]*P[nk][m]. Output channel = h*64 + d.
// ---------------------------------------------------------------------------
__global__ __launch_bounds__(256) void attn_kernel(const float* __restrict__ qkv,
                                                   float* __restrict__ hbuf) {
    const int qt = blockIdx.x;       // query tile 0..15
    const int bh = blockIdx.y;       // 0..63
    const int b = bh >> 3;
    const int h = bh & 7;
    const int tid = threadIdx.x;
    const int tx = tid & 15;         // m direction (queries)
    const int ty = tid >> 4;         // nk / d direction
    const int m0 = qt * 64;

    __shared__ __align__(16) float Qs[64][68];  // [d][m]
    __shared__ __align__(16) float KV[64][68];  // [d][nk] (K, then V)
    __shared__ __align__(16) float Ss[64][68];  // [nk][m] scores -> probs
    __shared__ float mrun[64], lrun[64], alphaS[64];

    const float* qbase = qkv + ((size_t)b * k3C + (size_t)h * 192) * kN;
    const float* kbase = qbase + (size_t)64 * kN;
    const float* vbase = qbase + (size_t)128 * kN;

    // Load Q tile [64 d][64 m]
    {
        const int m = tid & 63;
        const int dbase = tid >> 6;  // 0..3
#pragma unroll
        for (int i = 0; i < 16; i++) {
            const int d = dbase + i * 4;
            Qs[d][m] = qbase[(size_t)d * kN + m0 + m];
        }
    }
    if (tid < 64) { mrun[tid] = -INFINITY; lrun[tid] = 0.f; }
    float O[4][4] = {};
    __syncthreads();

    for (int kt = 0; kt < 16; kt++) {
        const int n0 = kt * 64;
        // Phase 1: load K tile into KV[d][nk]
        {
            const int nk = tid & 63;
            const int dbase = tid >> 6;
#pragma unroll
            for (int i = 0; i < 16; i++) {
                const int d = dbase + i * 4;
                KV[d][nk] = kbase[(size_t)d * kN + n0 + nk];
            }
        }
        __syncthreads();
        // Phase 2: S = scale * K^T Q (thread tile: nk = ty*4.., m = tx*4..)
        {
            float acc[4][4] = {};
#pragma unroll 8
            for (int d = 0; d < 64; d++) {
                float4 kf = *(const float4*)&KV[d][ty * 4];
                float4 qf = *(const float4*)&Qs[d][tx * 4];
                const float ka[4] = {kf.x, kf.y, kf.z, kf.w};
                const float qa[4] = {qf.x, qf.y, qf.z, qf.w};
#pragma unroll
                for (int i = 0; i < 4; i++)
#pragma unroll
                    for (int j = 0; j < 4; j++)
                        acc[i][j] = fmaf(ka[i], qa[j], acc[i][j]);
            }
#pragma unroll
            for (int i = 0; i < 4; i++)
#pragma unroll
                for (int j = 0; j < 4; j++)
                    Ss[ty * 4 + i][tx * 4 + j] = acc[i][j] * kScale;
        }
        __syncthreads();
        // Phase 3: all threads load V into KV[d][nk]; lanes <64 do softmax on Ss
        {
            const int nk = tid & 63;
            const int dbase = tid >> 6;
#pragma unroll
            for (int i = 0; i < 16; i++) {
                const int d = dbase + i * 4;
                KV[d][nk] = vbase[(size_t)d * kN + n0 + nk];
            }
        }
        if (tid < 64) {
            const int m = tid;
            const float mold = mrun[m];
            float tmax = -INFINITY;
#pragma unroll 8
            for (int nk = 0; nk < 64; nk++) tmax = fmaxf(tmax, Ss[nk][m]);
            const float mnew = fmaxf(mold, tmax);
            const float al = __expf(mold - mnew);  // exp(-inf)=0 on first tile
            float sum = 0.f;
#pragma unroll 8
            for (int nk = 0; nk < 64; nk++) {
                const float p = __expf(Ss[nk][m] - mnew);
                Ss[nk][m] = p;
                sum += p;
            }
            lrun[m] = lrun[m] * al + sum;
            mrun[m] = mnew;
            alphaS[m] = al;
        }
        __syncthreads();
        // Phase 4: rescale O, accumulate O += V @ P
        {
            float al[4];
#pragma unroll
            for (int j = 0; j < 4; j++) al[j] = alphaS[tx * 4 + j];
#pragma unroll
            for (int i = 0; i < 4; i++)
#pragma unroll
                for (int j = 0; j < 4; j++) O[i][j] *= al[j];
#pragma unroll 8
            for (int nk = 0; nk < 64; nk++) {
                float v[4];
#pragma unroll
                for (int i = 0; i < 4; i++) v[i] = KV[ty * 4 + i][nk];  // broadcast
                float4 pf = *(const float4*)&Ss[nk][tx * 4];
                const float pa[4] = {pf.x, pf.y, pf.z, pf.w};
#pragma unroll
                for (int i = 0; i < 4; i++)
#pragma unroll
                    for (int j = 0; j < 4; j++)
                        O[i][j] = fmaf(v[i], pa[j], O[i][j]);
            }
        }
        __syncthreads();
    }

    // Epilogue: divide by softmax denom, write hbuf[b][h*64 + d][m]
    float linv[4];
#pragma unroll
    for (int j = 0; j < 4; j++) linv[j] = 1.f / lrun[tx * 4 + j];
    float* ob = hbuf + ((size_t)b * kC + (size_t)h * kHD) * kN;
#pragma unroll
    for (int i = 0; i < 4; i++) {
        const int d = ty * 4 + i;
        float4 st;
        st.x = O[i][0] * linv[0];
        st.y = O[i][1] * linv[1];
        st.z = O[i][2] * linv[2];
        st.w = O[i][3] * linv[3];
        *(float4*)&ob[(size_t)d * kN + m0 + tx * 4] = st;
    }
}

extern "C" void kernel_launch(void* const* d_in, const int* in_sizes, int n_in,
                              void* d_out, int out_size, void* d_ws, size_t ws_size,
                              hipStream_t stream) {
    const float* x      = (const float*)d_in[0];  // [8,512,32,32]
    const float* w_qkv  = (const float*)d_in[1];  // [1536,512]
    const float* w_proj = (const float*)d_in[2];  // [512,512]
    const float* b_proj = (const float*)d_in[3];  // [512]
    float* out = (float*)d_out;                   // [8,512,32,32]

    float* qkv  = (float*)d_ws;                          // [8][1536][1024] = 50.3 MB
    float* hbuf = qkv + (size_t)kB * k3C * kN;           // [8][512][1024]  = 16.8 MB

    dim3 blk(256);
    // QKV: [1536,512] x [512,1024] per batch
    gemm_wx<<<dim3(kN / 128, k3C / 128, kB), blk, 0, stream>>>(w_qkv, x, qkv, nullptr, k3C);
    // Fused attention: 64 (b,h) pairs x 16 query tiles
    attn_kernel<<<dim3(16, 64), blk, 0, stream>>>(qkv, hbuf);
    // Proj: [512,512] x [512,1024] per batch + bias
    gemm_wx<<<dim3(kN / 128, kC / 128, kB), blk, 0, stream>>>(w_proj, hbuf, out, b_proj, kC);
}

// Round 2
// 280.796 us; speedup vs baseline: 2.1411x; 2.1411x over previous
//
#include <hip/hip_runtime.h>
#include <math.h>

// ============================================================================
// Attention block (B=8, C=512, H=W=32, nh=8, hd=64) via bf16x3 MFMA.
// fp32 values split as hi+lo bf16; products use 3 MFMAs (AhBh+AhBl+AlBh).
// Pipeline (2 half-batch passes to keep ws at ~54.5 MB):
//   split_w:  w_qkv/w_proj fp32 -> hi/lo bf16 planes [o][c] (k-contiguous)
//   split_x:  x[b][c][n] fp32 -> xt hi/lo [b][n][c]  (transposed, k-contig)
//   gemm_qkv: 128x128 tile bf16x3 MFMA; epilogue writes Q(*0.125)/K
//             transposed [b][h][n][d] as u32(hi<<16|lo), V natural [b][h][d][n]
//   attn:     flash-style, Q-frags in regs, K/V/P in LDS, MFMA QK^T and PV,
//             P as single bf16; epilogue -> hT hi/lo [b][n][c]
//   gemm_proj: bf16x3 MFMA + bias -> out fp32
// ============================================================================

typedef unsigned int u32;
typedef float  f32x4 __attribute__((ext_vector_type(4)));
typedef short  s16x8 __attribute__((ext_vector_type(8)));
typedef unsigned short u16x4 __attribute__((ext_vector_type(4)));
typedef unsigned int   u32x4 __attribute__((ext_vector_type(4)));

#define MFMA16(a, b, c) __builtin_amdgcn_mfma_f32_16x16x32_bf16(a, b, c, 0, 0, 0)

// split fp32 -> (hi bf16 << 16) | lo bf16.  hi = truncation, lo = RNE(f - hi)
__device__ __forceinline__ u32 splitpack(float f) {
    u32 b = __float_as_uint(f);
    u32 hb = b & 0xFFFF0000u;
    float lf = f - __uint_as_float(hb);
    u32 lb = __float_as_uint(lf);
    u32 lr = (lb + 0x7FFFu + ((lb >> 16) & 1u)) >> 16;
    return hb | (lr & 0xFFFFu);
}
__device__ __forceinline__ ushort f2bf(float f) {  // RNE fp32->bf16
    u32 b = __float_as_uint(f);
    return (ushort)((b + 0x7FFFu + ((b >> 16) & 1u)) >> 16);
}
__device__ __forceinline__ void unpack4(u32x4 v, u16x4& hi, u16x4& lo) {
    hi[0] = (ushort)(v.x >> 16); hi[1] = (ushort)(v.y >> 16);
    hi[2] = (ushort)(v.z >> 16); hi[3] = (ushort)(v.w >> 16);
    lo[0] = (ushort)v.x; lo[1] = (ushort)v.y;
    lo[2] = (ushort)v.z; lo[3] = (ushort)v.w;
}
__device__ __forceinline__ void unpack8(u32x4 a0, u32x4 a1, s16x8& hi, s16x8& lo) {
    hi[0]=(short)(a0.x>>16); hi[1]=(short)(a0.y>>16); hi[2]=(short)(a0.z>>16); hi[3]=(short)(a0.w>>16);
    hi[4]=(short)(a1.x>>16); hi[5]=(short)(a1.y>>16); hi[6]=(short)(a1.z>>16); hi[7]=(short)(a1.w>>16);
    lo[0]=(short)a0.x; lo[1]=(short)a0.y; lo[2]=(short)a0.z; lo[3]=(short)a0.w;
    lo[4]=(short)a1.x; lo[5]=(short)a1.y; lo[6]=(short)a1.z; lo[7]=(short)a1.w;
}

// ---------------------------------------------------------------------------
// split_w: both weight matrices -> hi/lo bf16 planes, same [o][c] layout.
// ---------------------------------------------------------------------------
__global__ __launch_bounds__(256) void split_w(const float* __restrict__ wq,
                                               const float* __restrict__ wp,
                                               ushort* __restrict__ wq_h, ushort* __restrict__ wq_l,
                                               ushort* __restrict__ wp_h, ushort* __restrict__ wp_l) {
    size_t base = ((size_t)blockIdx.x * 256 + threadIdx.x) * 4;
    const float* src; ushort *dh, *dl; size_t off;
    if (base < 786432) { src = wq; dh = wq_h; dl = wq_l; off = base; }
    else               { src = wp; dh = wp_h; dl = wp_l; off = base - 786432; }
    f32x4 v = *(const f32x4*)(src + off);
    u16x4 hi, lo;
#pragma unroll
    for (int e = 0; e < 4; e++) { u32 pk = splitpack(v[e]); hi[e] = (ushort)(pk >> 16); lo[e] = (ushort)pk; }
    *(u16x4*)(dh + off) = hi;
    *(u16x4*)(dl + off) = lo;
}

// ---------------------------------------------------------------------------
// split_x: x[b][c][n] fp32 -> xt hi/lo [bl][n][c] bf16 (64x64 tile transpose).
// ---------------------------------------------------------------------------
__global__ __launch_bounds__(256) void split_x(const float* __restrict__ x,
                                               ushort* __restrict__ xh, ushort* __restrict__ xl,
                                               int bbase) {
    __shared__ __align__(16) ushort Th[64 * 72];
    __shared__ __align__(16) ushort Tl[64 * 72];
    const int t = threadIdx.x;
    const int n0 = blockIdx.x * 64, c0 = blockIdx.y * 64, bz = blockIdx.z;
    const int b = bbase + bz;
    const int c = t >> 2, nseg = (t & 3) * 4;
    const float* src = x + ((size_t)b * 512 + c0 + c) * 1024 + n0;
#pragma unroll
    for (int i = 0; i < 4; i++) {
        f32x4 v = *(const f32x4*)(src + nseg + i * 16);
#pragma unroll
        for (int e = 0; e < 4; e++) {
            u32 pk = splitpack(v[e]);
            int nl = nseg + i * 16 + e;
            Th[nl * 72 + c] = (ushort)(pk >> 16);
            Tl[nl * 72 + c] = (ushort)pk;
        }
    }
    __syncthreads();
#pragma unroll
    for (int i = 0; i < 2; i++) {
        int nl = i * 32 + (t >> 3);
        int u = t & 7;
        s16x8 vh = *(const s16x8*)(Th + nl * 72 + u * 8);
        s16x8 vl = *(const s16x8*)(Tl + nl * 72 + u * 8);
        size_t go = ((size_t)bz * 1024 + n0 + nl) * 512 + c0 + u * 8;
        *(s16x8*)(xh + go) = vh;
        *(s16x8*)(xl + go) = vl;
    }
}

// ---------------------------------------------------------------------------
// Shared bf16x3 GEMM mainloop: 128x128 tile, BK=32, reg-prefetched staging.
// acc[Mt][Nt]: D rows o = ohalf*64+Mt*16+quad*4+r, cols n = nhalf*64+Nt*16+l15.
// ---------------------------------------------------------------------------
__device__ __forceinline__ void gemm_core(
    const ushort* __restrict__ Ah_g, const ushort* __restrict__ Al_g, int arow0,
    const ushort* __restrict__ Bh_g, const ushort* __restrict__ Bl_g, size_t brow0,
    ushort* smem, f32x4 (&acc)[4][4]) {
    const int t = threadIdx.x;
    ushort* As_h = smem;
    ushort* As_l = smem + 5120;
    ushort* Bs_h = smem + 10240;
    ushort* Bs_l = smem + 15360;
    const int ro = t >> 1, cs = (t & 1) << 4;
    const size_t ga = (size_t)(arow0 + ro) * 512 + cs;
    const size_t gb = (brow0 + ro) * 512 + cs;
    const int l15 = t & 15, quad = (t >> 4) & 3, wv = t >> 6;
    const int lra = (((wv >> 1) * 64) + l15) * 40 + quad * 8;
    const int lrb = (((wv & 1) * 64) + l15) * 40 + quad * 8;
    const int lw = ro * 40 + cs;

    s16x8 vah0 = *(const s16x8*)(Ah_g + ga),     vah1 = *(const s16x8*)(Ah_g + ga + 8);
    s16x8 val0 = *(const s16x8*)(Al_g + ga),     val1 = *(const s16x8*)(Al_g + ga + 8);
    s16x8 vbh0 = *(const s16x8*)(Bh_g + gb),     vbh1 = *(const s16x8*)(Bh_g + gb + 8);
    s16x8 vbl0 = *(const s16x8*)(Bl_g + gb),     vbl1 = *(const s16x8*)(Bl_g + gb + 8);

    for (int k0 = 0; k0 < 512; k0 += 32) {
        __syncthreads();
        *(s16x8*)(As_h + lw) = vah0; *(s16x8*)(As_h + lw + 8) = vah1;
        *(s16x8*)(As_l + lw) = val0; *(s16x8*)(As_l + lw + 8) = val1;
        *(s16x8*)(Bs_h + lw) = vbh0; *(s16x8*)(Bs_h + lw + 8) = vbh1;
        *(s16x8*)(Bs_l + lw) = vbl0; *(s16x8*)(Bs_l + lw + 8) = vbl1;
        const int kn = (k0 + 32) & 511;  // wraps to 0 on last iter (discarded)
        vah0 = *(const s16x8*)(Ah_g + ga + kn); vah1 = *(const s16x8*)(Ah_g + ga + kn + 8);
        val0 = *(const s16x8*)(Al_g + ga + kn); val1 = *(const s16x8*)(Al_g + ga + kn + 8);
        vbh0 = *(const s16x8*)(Bh_g + gb + kn); vbh1 = *(const s16x8*)(Bh_g + gb + kn + 8);
        vbl0 = *(const s16x8*)(Bl_g + gb + kn); vbl1 = *(const s16x8*)(Bl_g + gb + kn + 8);
        __syncthreads();
        s16x8 ah[4], al[4], bh[4], bl[4];
#pragma unroll
        for (int Mt = 0; Mt < 4; Mt++) {
            ah[Mt] = *(const s16x8*)(As_h + lra + Mt * 640);
            al[Mt] = *(const s16x8*)(As_l + lra + Mt * 640);
        }
#pragma unroll
        for (int Nt = 0; Nt < 4; Nt++) {
            bh[Nt] = *(const s16x8*)(Bs_h + lrb + Nt * 640);
            bl[Nt] = *(const s16x8*)(Bs_l + lrb + Nt * 640);
        }
#pragma unroll
        for (int Mt = 0; Mt < 4; Mt++)
#pragma unroll
            for (int Nt = 0; Nt < 4; Nt++) {
                acc[Mt][Nt] = MFMA16(ah[Mt], bh[Nt], acc[Mt][Nt]);
                acc[Mt][Nt] = MFMA16(ah[Mt], bl[Nt], acc[Mt][Nt]);
                acc[Mt][Nt] = MFMA16(al[Mt], bh[Nt], acc[Mt][Nt]);
            }
    }
    __syncthreads();  // LDS free for epilogue reuse
}

// ---------------------------------------------------------------------------
// QKV GEMM. o-halves (64 rows) align exactly to q/k/v roles: g = ot*2+ohalf,
// role = g%3 (0=q,1=k,2=v), head = g/3.  Q/K go through an LDS transpose to
// [b][h][n][d] u32(hi|lo); V stored natural [b][h][d][n] u32.
// ---------------------------------------------------------------------------
__global__ __launch_bounds__(256) void gemm_qkv(
    const ushort* __restrict__ wq_h, const ushort* __restrict__ wq_l,
    const ushort* __restrict__ xt_h, const ushort* __restrict__ xt_l,
    u32* __restrict__ qT, u32* __restrict__ kT, u32* __restrict__ vI) {
    __shared__ __align__(16) ushort smem[20480];
    f32x4 acc[4][4];
#pragma unroll
    for (int i = 0; i < 4; i++)
#pragma unroll
        for (int j = 0; j < 4; j++) acc[i][j] = (f32x4)0.0f;

    const int n0 = blockIdx.x * 128, o0 = blockIdx.y * 128, bz = blockIdx.z;
    gemm_core(wq_h, wq_l, o0, xt_h, xt_l, (size_t)bz * 1024 + n0, smem, acc);

    const int t = threadIdx.x;
    const int l15 = t & 15, quad = (t >> 4) & 3, wv = t >> 6, lane = t & 63;
    const int g = blockIdx.y * 2 + (wv >> 1);
    const int role = g % 3, head = g / 3;
    const int nh = (wv & 1) * 64;
    const size_t hb = (size_t)bz * 8 + head;
    const float scale = (role == 0) ? 0.125f : 1.0f;

    if (role < 2) {
        u32* dst = (role == 0) ? qT : kT;
        u32* T = (u32*)smem + wv * 2304;             // per-wave [64 n][36] u32
        const size_t rowbase = hb * 1024 + n0 + nh;  // pixel row index
#pragma unroll
        for (int sp = 0; sp < 2; sp++) {
#pragma unroll
            for (int Mti = 0; Mti < 2; Mti++)
#pragma unroll
                for (int Nt = 0; Nt < 4; Nt++) {
                    f32x4 v = acc[sp * 2 + Mti][Nt];
                    u32x4 pix;
#pragma unroll
                    for (int r = 0; r < 4; r++) pix[r] = splitpack(v[r] * scale);
                    *(u32x4*)(T + (Nt * 16 + l15) * 36 + Mti * 16 + quad * 4) = pix;
                }
            asm volatile("s_waitcnt lgkmcnt(0)" ::: "memory");
#pragma unroll
            for (int i = 0; i < 8; i++) {
                int nl = i * 8 + (lane >> 3);
                u32x4 vv = *(const u32x4*)(T + nl * 36 + (lane & 7) * 4);
                *(u32x4*)(dst + (rowbase + nl) * 64 + sp * 32 + (lane & 7) * 4) = vv;
            }
            asm volatile("s_waitcnt lgkmcnt(0)" ::: "memory");
        }
    } else {
        const size_t vb = hb * 64 * 1024 + (size_t)(n0 + nh);
#pragma unroll
        for (int Mt = 0; Mt < 4; Mt++)
#pragma unroll
            for (int Nt = 0; Nt < 4; Nt++)
#pragma unroll
                for (int r = 0; r < 4; r++) {
                    u32 pk = splitpack(acc[Mt][Nt][r]);
                    vI[vb + (size_t)(Mt * 16 + quad * 4 + r) * 1024 + Nt * 16 + l15] = pk;
                }
    }
}

// ---------------------------------------------------------------------------
// Proj GEMM: out fp32 + bias, direct C/D stores.
// ---------------------------------------------------------------------------
__global__ __launch_bounds__(256) void gemm_proj(
    const ushort* __restrict__ wp_h, const ushort* __restrict__ wp_l,
    const ushort* __restrict__ ht_h, const ushort* __restrict__ ht_l,
    const float* __restrict__ bias, float* __restrict__ out) {
    __shared__ __align__(16) ushort smem[20480];
    f32x4 acc[4][4];
#pragma unroll
    for (int i = 0; i < 4; i++)
#pragma unroll
        for (int j = 0; j < 4; j++) acc[i][j] = (f32x4)0.0f;

    const int n0 = blockIdx.x * 128, o0 = blockIdx.y * 128, bz = blockIdx.z;
    gemm_core(wp_h, wp_l, o0, ht_h, ht_l, (size_t)bz * 1024 + n0, smem, acc);

    const int t = threadIdx.x;
    const int l15 = t & 15, quad = (t >> 4) & 3, wv = t >> 6;
#pragma unroll
    for (int Mt = 0; Mt < 4; Mt++)
#pragma unroll
        for (int Nt = 0; Nt < 4; Nt++) {
            int ob = o0 + (wv >> 1) * 64 + Mt * 16 + quad * 4;
            int nn = n0 + (wv & 1) * 64 + Nt * 16 + l15;
#pragma unroll
            for (int r = 0; r < 4; r++)
                out[((size_t)bz * 512 + ob + r) * 1024 + nn] = acc[Mt][Nt][r] + bias[ob + r];
        }
}

// ---------------------------------------------------------------------------
// Flash attention, bf16x3 MFMA.  Block: one (b,h), 128-query tile, 16 key
// tiles of 64.  Q-frags persistent in registers; K/V/P in LDS (36.9 KB).
// S[nk][m] = Kt_frag x Qt_frag (D col=m, row=nk); softmax over nk per col m
// via XOR-16/32 shuffles (stats wave-local); P single bf16; O += V x P.
// ---------------------------------------------------------------------------
__global__ __launch_bounds__(256) void attn_mfma(
    const u32* __restrict__ qT, const u32* __restrict__ kT, const u32* __restrict__ vI,
    ushort* __restrict__ ht_h, ushort* __restrict__ ht_l, int bbase) {
    __shared__ __align__(16) ushort sm[18432];  // 36,864 B
    ushort* KVh = sm;           // [64][72]
    ushort* KVl = sm + 4608;
    ushort* Ps  = sm + 9216;    // [128][72] bf16 probs
    const int t = threadIdx.x;
    const int qt = blockIdx.x, bh = blockIdx.y;
    const int bl = bh >> 3, h = bh & 7;
    const int m0 = qt * 128;
    const size_t hb = (size_t)bl * 8 + h;
    const int l15 = t & 15, quad = (t >> 4) & 3, wv = t >> 6;

    // Persistent Q fragments (already scaled by 0.125 in gemm_qkv)
    s16x8 qfh[2][2], qfl[2][2];  // [Nt][ks]
#pragma unroll
    for (int Nt = 0; Nt < 2; Nt++)
#pragma unroll
        for (int ks = 0; ks < 2; ks++) {
            const u32* qp = qT + (hb * 1024 + m0 + (wv * 2 + Nt) * 16 + l15) * 64 + ks * 32 + quad * 8;
            u32x4 a0 = *(const u32x4*)(qp);
            u32x4 a1 = *(const u32x4*)(qp + 4);
            unpack8(a0, a1, qfh[Nt][ks], qfl[Nt][ks]);
        }

    f32x4 O[4][2];
#pragma unroll
    for (int i = 0; i < 4; i++) { O[i][0] = (f32x4)0.0f; O[i][1] = (f32x4)0.0f; }
    float mrun[2] = {-3.0e38f, -3.0e38f}, lrun[2] = {0.f, 0.f};

    const u32* ksrc = kT + hb * 1024 * 64;
    const u32* vsrc = vI + hb * 64 * 1024;

    for (int kt = 0; kt < 16; kt++) {
        __syncthreads();  // prev O-phase done with KV
        {   // stage K tile [64 nk][64 d]
            const int nk = t >> 2;
#pragma unroll
            for (int i = 0; i < 4; i++) {
                int u = i * 4 + (t & 3);
                u32x4 v = *(const u32x4*)(ksrc + ((size_t)(kt * 64 + nk)) * 64 + u * 4);
                u16x4 hi, lo; unpack4(v, hi, lo);
                *(u16x4*)(KVh + nk * 72 + u * 4) = hi;
                *(u16x4*)(KVl + nk * 72 + u * 4) = lo;
            }
        }
        __syncthreads();
        // S = K^T Q
        f32x4 S[4][2];
#pragma unroll
        for (int i = 0; i < 4; i++) { S[i][0] = (f32x4)0.0f; S[i][1] = (f32x4)0.0f; }
#pragma unroll
        for (int ks = 0; ks < 2; ks++) {
            s16x8 kh[4], kl[4];
#pragma unroll
            for (int Mt = 0; Mt < 4; Mt++) {
                kh[Mt] = *(const s16x8*)(KVh + (Mt * 16 + l15) * 72 + ks * 32 + quad * 8);
                kl[Mt] = *(const s16x8*)(KVl + (Mt * 16 + l15) * 72 + ks * 32 + quad * 8);
            }
#pragma unroll
            for (int Mt = 0; Mt < 4; Mt++)
#pragma unroll
                for (int Nt = 0; Nt < 2; Nt++) {
                    S[Mt][Nt] = MFMA16(kh[Mt], qfh[Nt][ks], S[Mt][Nt]);
                    S[Mt][Nt] = MFMA16(kh[Mt], qfl[Nt][ks], S[Mt][Nt]);
                    S[Mt][Nt] = MFMA16(kl[Mt], qfh[Nt][ks], S[Mt][Nt]);
                }
        }
        // online softmax over nk (rows) per column m
        float alpha[2];
#pragma unroll
        for (int Nt = 0; Nt < 2; Nt++) {
            float tm = -3.0e38f;
#pragma unroll
            for (int Mt = 0; Mt < 4; Mt++)
#pragma unroll
                for (int r = 0; r < 4; r++) tm = fmaxf(tm, S[Mt][Nt][r]);
            tm = fmaxf(tm, __shfl_xor(tm, 16));
            tm = fmaxf(tm, __shfl_xor(tm, 32));
            float mnew = fmaxf(mrun[Nt], tm);
            alpha[Nt] = __expf(mrun[Nt] - mnew);
            float ts = 0.f;
#pragma unroll
            for (int Mt = 0; Mt < 4; Mt++)
#pragma unroll
                for (int r = 0; r < 4; r++) {
                    float p = __expf(S[Mt][Nt][r] - mnew);
                    S[Mt][Nt][r] = p;
                    ts += p;
                }
            ts += __shfl_xor(ts, 16);
            ts += __shfl_xor(ts, 32);
            lrun[Nt] = lrun[Nt] * alpha[Nt] + ts;
            mrun[Nt] = mnew;
        }
        // write P (bf16) to LDS [m][nk]
#pragma unroll
        for (int Mt = 0; Mt < 4; Mt++)
#pragma unroll
            for (int Nt = 0; Nt < 2; Nt++) {
                u16x4 pb;
#pragma unroll
                for (int r = 0; r < 4; r++) pb[r] = f2bf(S[Mt][Nt][r]);
                *(u16x4*)(Ps + ((wv * 2 + Nt) * 16 + l15) * 72 + Mt * 16 + quad * 4) = pb;
            }
        __syncthreads();  // all waves done reading K
        {   // stage V tile [64 d][64 nk] over K
            const int d = t >> 2;
#pragma unroll
            for (int i = 0; i < 4; i++) {
                int u = i * 4 + (t & 3);
                u32x4 v = *(const u32x4*)(vsrc + (size_t)d * 1024 + kt * 64 + u * 4);
                u16x4 hi, lo; unpack4(v, hi, lo);
                *(u16x4*)(KVh + d * 72 + u * 4) = hi;
                *(u16x4*)(KVl + d * 72 + u * 4) = lo;
            }
        }
        __syncthreads();
        // O = O*alpha + V @ P
#pragma unroll
        for (int Mt = 0; Mt < 4; Mt++)
#pragma unroll
            for (int Nt = 0; Nt < 2; Nt++) O[Mt][Nt] *= alpha[Nt];
#pragma unroll
        for (int ks = 0; ks < 2; ks++) {
            s16x8 vh[4], vl[4], pb2[2];
#pragma unroll
            for (int Mt = 0; Mt < 4; Mt++) {
                vh[Mt] = *(const s16x8*)(KVh + (Mt * 16 + l15) * 72 + ks * 32 + quad * 8);
                vl[Mt] = *(const s16x8*)(KVl + (Mt * 16 + l15) * 72 + ks * 32 + quad * 8);
            }
#pragma unroll
            for (int Nt = 0; Nt < 2; Nt++)
                pb2[Nt] = *(const s16x8*)(Ps + ((wv * 2 + Nt) * 16 + l15) * 72 + ks * 32 + quad * 8);
#pragma unroll
            for (int Mt = 0; Mt < 4; Mt++)
#pragma unroll
                for (int Nt = 0; Nt < 2; Nt++) {
                    O[Mt][Nt] = MFMA16(vh[Mt], pb2[Nt], O[Mt][Nt]);
                    O[Mt][Nt] = MFMA16(vl[Mt], pb2[Nt], O[Mt][Nt]);
                }
        }
    }

    // epilogue: O /= l, split hi/lo, LDS gather -> coalesced hT stores
    __syncthreads();  // all waves done with KV/Ps before overwrite
    ushort* OLh = sm;          // [128][72]
    ushort* OLl = sm + 9216;
    float linv[2] = {1.f / lrun[0], 1.f / lrun[1]};
#pragma unroll
    for (int Mt = 0; Mt < 4; Mt++)
#pragma unroll
        for (int Nt = 0; Nt < 2; Nt++) {
            u16x4 hi, lo;
#pragma unroll
            for (int r = 0; r < 4; r++) {
                u32 pk = splitpack(O[Mt][Nt][r] * linv[Nt]);
                hi[r] = (ushort)(pk >> 16);
                lo[r] = (ushort)pk;
            }
            int m = (wv * 2 + Nt) * 16 + l15;
            *(u16x4*)(OLh + m * 72 + Mt * 16 + quad * 4) = hi;
            *(u16x4*)(OLl + m * 72 + Mt * 16 + quad * 4) = lo;
        }
    __syncthreads();
    const size_t ob = (size_t)(bbase + bl) * 1024 + m0;
#pragma unroll
    for (int i = 0; i < 4; i++) {
        int m = i * 32 + (t >> 3);
        int u = t & 7;
        s16x8 vh2 = *(const s16x8*)(OLh + m * 72 + u * 8);
        s16x8 vl2 = *(const s16x8*)(OLl + m * 72 + u * 8);
        size_t go = (ob + m) * 512 + h * 64 + u * 8;
        *(s16x8*)(ht_h + go) = vh2;
        *(s16x8*)(ht_l + go) = vl2;
    }
}

// ---------------------------------------------------------------------------
extern "C" void kernel_launch(void* const* d_in, const int* in_sizes, int n_in,
                              void* d_out, int out_size, void* d_ws, size_t ws_size,
                              hipStream_t stream) {
    (void)in_sizes; (void)n_in; (void)out_size; (void)ws_size;
    const float* x      = (const float*)d_in[0];
    const float* w_qkv  = (const float*)d_in[1];
    const float* w_proj = (const float*)d_in[2];
    const float* b_proj = (const float*)d_in[3];
    float* out = (float*)d_out;

    // workspace layout (bytes), total 54,525,952 (< 67 MB proven safe)
    char* ws = (char*)d_ws;
    ushort* xt_h = (ushort*)(ws);                       // 4,194,304
    ushort* xt_l = (ushort*)(ws + 4194304);             // 4,194,304
    ushort* wq_h = (ushort*)(ws + 8388608);             // 1,572,864
    ushort* wq_l = (ushort*)(ws + 9961472);             // 1,572,864
    ushort* wp_h = (ushort*)(ws + 11534336);            //   524,288
    ushort* wp_l = (ushort*)(ws + 12058624);            //   524,288
    u32*    qT   = (u32*)   (ws + 12582912);            // 8,388,608
    u32*    kT   = (u32*)   (ws + 20971520);            // 8,388,608
    u32*    vI   = (u32*)   (ws + 29360128);            // 8,388,608
    ushort* ht_h = (ushort*)(ws + 37748736);            // 8,388,608
    ushort* ht_l = (ushort*)(ws + 46137344);            // 8,388,608

    split_w<<<1024, 256, 0, stream>>>(w_qkv, w_proj, wq_h, wq_l, wp_h, wp_l);
    for (int p = 0; p < 2; p++) {
        int bbase = p * 4;
        split_x<<<dim3(16, 8, 4), 256, 0, stream>>>(x, xt_h, xt_l, bbase);
        gemm_qkv<<<dim3(8, 12, 4), 256, 0, stream>>>(wq_h, wq_l, xt_h, xt_l, qT, kT, vI);
        attn_mfma<<<dim3(8, 32), 256, 0, stream>>>(qT, kT, vI, ht_h, ht_l, bbase);
    }
    gemm_proj<<<dim3(8, 4, 8), 256, 0, stream>>>(wp_h, wp_l, ht_h, ht_l, b_proj, out);
}